// Round 4
// baseline (1526.273 us; speedup 1.0000x reference)
//
#include <hip/hip_runtime.h>
#include <hip/hip_bf16.h>
#include <hip/hip_fp16.h>

// ============================================================================
// MinGRUCell forward, MI355X (gfx950).  Round 9 = single-pass GEMM+scan.
//
//   zh = x @ W'^T + b'   (W rows permuted: z/h 16-col blocks alternate)
//   gates a = sigmoid(-z), v = sigmoid(z)*g(h_inter) held IN REGISTERS
//   h[t] = a*h[t-1] + v solved in the SAME kernel via decoupled lookback:
//     - ticket (atomicAdd) ordering => block only waits on lower tickets
//       => no deadlock regardless of dispatch order (rocPRIM pattern)
//     - per-block 128-row affine aggregate published (flag=1), inclusive
//       h-prefix published after lookback (flag=2); __hip_atomic AGENT scope
//       + __threadfence for cross-XCD visibility
//     - replay writes `out` directly (nontemporal)
//
// DELETED vs round 8: avbuf (128 MiB write + 128 MiB read), Aar/Bar/seed,
// scan_phase2, scan_phase3.  Post-GEMM HBM traffic is now just `out`.
//
// Workspace: wb 4MiB | xb 64MiB | biasp 8KiB | state 3MiB | flags+ticket 33KiB
// ============================================================================

#define N_B   8
#define L_SEQ 4096
#define H_DIM 1024
#define K_DIM 1024
#define O_DIM 2048
#define M_TOT (N_B * L_SEQ)      // 32768 GEMM rows

#define BM 128
#define BN 128
#define BK 64
#define TILES_M (M_TOT / BM)     // 256
#define TILES_N (O_DIM / BN)     // 16
#define NTILES  (TILES_M * TILES_N)   // 4096
#define MT_PER_BATCH (L_SEQ / BM)     // 32

typedef unsigned short ushort_t;
typedef unsigned short us8 __attribute__((ext_vector_type(8)));
typedef __bf16 v8bf __attribute__((ext_vector_type(8)));
typedef float f32x4 __attribute__((ext_vector_type(4)));

static __device__ __forceinline__ ushort_t f2bf(float f) {
    __hip_bfloat16 h = __float2bfloat16(f);   // RTN
    return *reinterpret_cast<ushort_t*>(&h);
}

// async global->LDS DMA, 16B per lane, LDS dest = wave-uniform base + lane*16
static __device__ __forceinline__ void dma16(const ushort_t* g, ushort_t* l) {
    __builtin_amdgcn_global_load_lds(
        (const __attribute__((address_space(1))) unsigned int*)g,
        (__attribute__((address_space(3))) unsigned int*)l,
        16, 0, 0);
}

// agent-scope (device) atomics for cross-XCD scan state
static __device__ __forceinline__ float ald(const float* p) {
    return __hip_atomic_load(p, __ATOMIC_RELAXED, __HIP_MEMORY_SCOPE_AGENT);
}
static __device__ __forceinline__ void ast(float* p, float v) {
    __hip_atomic_store(p, v, __ATOMIC_RELAXED, __HIP_MEMORY_SCOPE_AGENT);
}

// ---------------------------------------------------------------------------
// init: zero flags (2 per tile) + ticket.  Runs every launch (graph replay).
// ---------------------------------------------------------------------------
__global__ __launch_bounds__(256) void init_sync(int* __restrict__ flags)
{
    const int i = blockIdx.x * 256 + threadIdx.x;
    if (i <= NTILES * 2) flags[i] = 0;       // [0..8191]=flags, [8192]=ticket
}

// ---------------------------------------------------------------------------
// fp32 -> bf16 (8 elems/thread), straight copy (used for X)
// ---------------------------------------------------------------------------
__global__ __launch_bounds__(256) void cvt_f32_bf16(
    const float* __restrict__ src, ushort_t* __restrict__ dst)
{
    const int i = blockIdx.x * 256 + threadIdx.x;
    const float4 f0 = ((const float4*)src)[2 * i];
    const float4 f1 = ((const float4*)src)[2 * i + 1];
    us8 o;
    o[0] = f2bf(f0.x); o[1] = f2bf(f0.y); o[2] = f2bf(f0.z); o[3] = f2bf(f0.w);
    o[4] = f2bf(f1.x); o[5] = f2bf(f1.y); o[6] = f2bf(f1.z); o[7] = f2bf(f1.w);
    ((us8*)dst)[i] = o;
}

// ---------------------------------------------------------------------------
// fp32 -> bf16 W with row permutation: dest row o' in 16-row blocks B=o'>>4,
// t=o'&15: B even -> z row (B>>1)*16+t ; B odd -> h row 1024+(B>>1)*16+t.
// ---------------------------------------------------------------------------
__global__ __launch_bounds__(256) void cvt_w_perm(
    const float* __restrict__ src, ushort_t* __restrict__ dst)
{
    const int i  = blockIdx.x * 256 + threadIdx.x;  // 262144 threads
    const int op = i >> 7;                          // dest row 0..2047
    const int k  = (i & 127) * 8;
    const int B  = op >> 4, t = op & 15;
    const int orig = (B & 1) * 1024 + (B >> 1) * 16 + t;
    const float4* s = (const float4*)(src + (size_t)orig * K_DIM + k);
    const float4 f0 = s[0], f1 = s[1];
    us8 o;
    o[0] = f2bf(f0.x); o[1] = f2bf(f0.y); o[2] = f2bf(f0.z); o[3] = f2bf(f0.w);
    o[4] = f2bf(f1.x); o[5] = f2bf(f1.y); o[6] = f2bf(f1.z); o[7] = f2bf(f1.w);
    *(us8*)(dst + (size_t)op * K_DIM + k) = o;
}

// bias with the same permutation (fp32)
__global__ __launch_bounds__(256) void bias_perm(
    const float* __restrict__ b, float* __restrict__ bp)
{
    const int i = blockIdx.x * 256 + threadIdx.x;   // 0..2047
    const int B = i >> 4, t = i & 15;
    bp[i] = b[(B & 1) * 1024 + (B >> 1) * 16 + t];
}

// ---------------------------------------------------------------------------
// Gating math.  a = sigmoid(-z), v = sigmoid(z)*g(hi)
// ---------------------------------------------------------------------------
__device__ __forceinline__ void gate_av(float z, float hi, float& a, float& v)
{
    const float e  = __expf(-z);
    const float sz = 1.0f / (1.0f + e);        // sigmoid(z)
    a = e * sz;                                // sigmoid(-z)
    const float g = (hi >= 0.0f) ? (hi + 0.5f)
                                 : (1.0f / (1.0f + __expf(-hi)));
    v = sz * g;
}

// ---------------------------------------------------------------------------
// Fused GEMM + gates + decoupled-lookback scan + output replay.
// state[tile]: 192 floats = Agg A[64] | Agg B[64] | h_prefix[64]
// flags[tile*2+half]: 0=empty, 1=aggregate ready, 2=prefix ready
// ---------------------------------------------------------------------------
__global__ __launch_bounds__(256) void gemm_scan(
    const ushort_t* __restrict__ Xb,       // (M_TOT, K) bf16 bits
    const ushort_t* __restrict__ Wb,       // (O_DIM, K) bf16 bits, PERMUTED
    const float* __restrict__ biasp,       // (O_DIM) fp32, PERMUTED
    const float* __restrict__ hx,          // (N_B, H_DIM) fp32
    float* __restrict__ out,               // (M_TOT, H_DIM) fp32
    float* __restrict__ st,                // (NTILES, 192) fp32
    int* __restrict__ flags)               // [NTILES*2] + ticket at [NTILES*2]
{
    __shared__ ushort_t As[BM * BK];
    __shared__ ushort_t Bs[BN * BK];
    __shared__ int s_id;

    const int tid    = threadIdx.x;
    const int wave   = tid >> 6;
    const int lane   = tid & 63;
    const int lane15 = lane & 15;
    const int quad   = lane >> 4;

    // ticket: start-order tile IDs -> lookback waits only on lower IDs
    if (tid == 0) s_id = atomicAdd(flags + NTILES * 2, 1);
    __syncthreads();
    const int id = s_id;
    const int m0 = (id >> 4) * BM;
    const int n0 = (id & 15) * BN;

    const int lrow = lane >> 3;            // 0..7
    const int jj   = (lane & 7) ^ lrow;    // global chunk (xor swizzle)
    const ushort_t* gA = Xb + (size_t)(m0 + wave * 8 + lrow) * K_DIM + jj * 8;
    const ushort_t* gB = Wb + (size_t)(n0 + wave * 8 + lrow) * K_DIM + jj * 8;
    ushort_t* lA = &As[(wave * 8) * BK];
    ushort_t* lB = &Bs[(wave * 8) * BK];

    const int wm = (wave >> 1) * 64;
    const int wn = (wave & 1) * 64;

    int offA[2][4], offB[2][4];
#pragma unroll
    for (int s = 0; s < 2; ++s) {
#pragma unroll
        for (int t = 0; t < 4; ++t) {
            const int rowA = wm + t * 16 + lane15;
            offA[s][t] = rowA * BK + (((s * 4 + quad) ^ (rowA & 7)) * 8);
            const int rowB = wn + t * 16 + lane15;
            offB[s][t] = rowB * BK + (((s * 4 + quad) ^ (rowB & 7)) * 8);
        }
    }

    const f32x4 fzero = {0.f, 0.f, 0.f, 0.f};
    f32x4 acc[4][4];
#pragma unroll
    for (int i = 0; i < 4; ++i)
#pragma unroll
        for (int j = 0; j < 4; ++j)
            acc[i][j] = fzero;

    for (int kt = 0; kt < K_DIM / BK; ++kt) {
        __syncthreads();
#pragma unroll
        for (int r = 0; r < 4; ++r) {
            dma16(gA + (size_t)r * 32 * K_DIM + kt * BK, lA + r * 32 * BK);
            dma16(gB + (size_t)r * 32 * K_DIM + kt * BK, lB + r * 32 * BK);
        }
        __syncthreads();

#pragma unroll
        for (int s = 0; s < 2; ++s) {
            v8bf af[4], bfr[4];
#pragma unroll
            for (int t = 0; t < 4; ++t) af[t]  = *(const v8bf*)(&As[offA[s][t]]);
#pragma unroll
            for (int t = 0; t < 4; ++t) bfr[t] = *(const v8bf*)(&Bs[offB[s][t]]);
#pragma unroll
            for (int i = 0; i < 4; ++i)
#pragma unroll
                for (int j = 0; j < 4; ++j)
                    acc[i][j] = __builtin_amdgcn_mfma_f32_16x16x32_bf16(
                        af[i], bfr[j], acc[i][j], 0, 0, 0);
        }
    }

    // ================= epilogue: gates -> registers ========================
    float bv[4];
#pragma unroll
    for (int j = 0; j < 4; ++j)
        bv[j] = biasp[n0 + wn + j * 16 + lane15];

    __half2 av[4][4][2];   // (a,v) per (i-frag, r, jp-channel) -- static idx
#pragma unroll
    for (int i = 0; i < 4; ++i)
#pragma unroll
        for (int r = 0; r < 4; ++r)
#pragma unroll
            for (int jp = 0; jp < 2; ++jp) {
                const float z  = acc[i][2 * jp][r]     + bv[2 * jp];
                const float hh = acc[i][2 * jp + 1][r] + bv[2 * jp + 1];
                float a, v;
                gate_av(z, hh, a, v);
                av[i][r][jp] = __floats2half2_rn(a, v);
            }

    // ---- per-(i,quad) 4-row runs: quad-exclusive prefixes + wave summary --
    // rows in wave: i*16 + quad*4 + r  (i outer, quad middle, r inner)
    float Aw[2] = {1.f, 1.f}, Bw[2] = {0.f, 0.f};   // wave 64-row summary
    float Aex[4][2], Bex[4][2];    // run-start map relative to WAVE start
#pragma unroll
    for (int i = 0; i < 4; ++i) {
#pragma unroll
        for (int jp = 0; jp < 2; ++jp) {
            float Ar = 1.f, Br = 0.f;              // 4-row run summary
#pragma unroll
            for (int r = 0; r < 4; ++r) {
                const float2 f = __half22float2(av[i][r][jp]);
                Br = fmaf(f.x, Br, f.y); Ar *= f.x;
            }
            // inclusive scan over quads (lanes l15, +16, +32, +48)
            float Au = __shfl_up(Ar, 16), Bu = __shfl_up(Br, 16);
            if (quad >= 1) { Br = fmaf(Ar, Bu, Br); Ar *= Au; }
            Au = __shfl_up(Ar, 32); Bu = __shfl_up(Br, 32);
            if (quad >= 2) { Br = fmaf(Ar, Bu, Br); Ar *= Au; }
            // exclusive
            float Ax = __shfl_up(Ar, 16), Bx = __shfl_up(Br, 16);
            if (quad == 0) { Ax = 1.f; Bx = 0.f; }
            // E = quadEx o (frags<i inclusive)
            Aex[i][jp] = Ax * Aw[jp];
            Bex[i][jp] = fmaf(Ax, Bw[jp], Bx);
            // frag inclusive = quad3's inclusive, broadcast
            const float Af = __shfl(Ar, 48 + lane15);
            const float Bf = __shfl(Br, 48 + lane15);
            Bw[jp] = fmaf(Af, Bw[jp], Bf); Aw[jp] *= Af;
        }
    }

    // ---- cross-wave combine + decoupled lookback --------------------------
    float* ldsf = (float*)As;            // reuse LDS (barrier-guarded)
    const int wn2 = wn >> 6;             // 0/1: which 32-channel half
    const int sl0 = wn2 * 32 + lane15;   // + jp*16  -> slot 0..63
    __syncthreads();                     // K-loop LDS reads done

    if (wm == 0 && lane < 16) {
#pragma unroll
        for (int jp = 0; jp < 2; ++jp) {
            ldsf[sl0 + jp * 16]      = Aw[jp];
            ldsf[64 + sl0 + jp * 16] = Bw[jp];
        }
    }
    __syncthreads();

    float hws[2];                        // h at this wave's first row - 1
    if (wm) {                            // wm==64 waves do the lookback
        float A0[2], B0[2], hin[2];
#pragma unroll
        for (int jp = 0; jp < 2; ++jp) {
            A0[jp] = ldsf[sl0 + jp * 16];
            B0[jp] = ldsf[64 + sl0 + jp * 16];
        }
        float Ab[2], Bb[2];              // block 128-row aggregate
#pragma unroll
        for (int jp = 0; jp < 2; ++jp) {
            Ab[jp] = Aw[jp] * A0[jp];
            Bb[jp] = fmaf(Aw[jp], B0[jp], Bw[jp]);
        }
        const int  mtile  = id >> 4;
        const bool bstart = (mtile & (MT_PER_BATCH - 1)) == 0;
        const size_t sb   = (size_t)id * 192;
        const int  fidx   = id * 2 + wn2;

        if (!bstart) {                   // publish aggregate early (flag=1)
            if (lane < 16) {
#pragma unroll
                for (int jp = 0; jp < 2; ++jp) {
                    ast(st + sb + sl0 + jp * 16, Ab[jp]);
                    ast(st + sb + 64 + sl0 + jp * 16, Bb[jp]);
                }
            }
            __threadfence();
            if (lane == 0)
                __hip_atomic_store(flags + fidx, 1, __ATOMIC_RELEASE,
                                   __HIP_MEMORY_SCOPE_AGENT);
        }

        if (bstart) {
#pragma unroll
            for (int jp = 0; jp < 2; ++jp)
                hin[jp] = hx[(size_t)(m0 >> 12) * H_DIM +
                             ((n0 + wn) >> 1) + lane15 + jp * 16];
        } else {
            float MA[2] = {1.f, 1.f}, MB[2] = {0.f, 0.f};
            int j = id - TILES_N;        // previous m-tile, same n-tile
            for (;;) {
                int f;
                do {
                    f = __hip_atomic_load(flags + j * 2 + wn2, __ATOMIC_ACQUIRE,
                                          __HIP_MEMORY_SCOPE_AGENT);
                    f = __builtin_amdgcn_readfirstlane(f);
                    if (!f) __builtin_amdgcn_s_sleep(2);
                } while (!f);
                const size_t jb = (size_t)j * 192;
                if (f == 2) {            // inclusive prefix available
#pragma unroll
                    for (int jp = 0; jp < 2; ++jp) {
                        const float hp = ald(st + jb + 128 + sl0 + jp * 16);
                        hin[jp] = fmaf(MA[jp], hp, MB[jp]);
                    }
                    break;
                }
                // aggregate only: accumulate and walk back
#pragma unroll
                for (int jp = 0; jp < 2; ++jp) {
                    const float Aj = ald(st + jb + sl0 + jp * 16);
                    const float Bj = ald(st + jb + 64 + sl0 + jp * 16);
                    MB[jp] = fmaf(MA[jp], Bj, MB[jp]); MA[jp] *= Aj;
                }
                j -= TILES_N;
            }
        }

        // publish inclusive prefix (flag=2)
        if (lane < 16) {
#pragma unroll
            for (int jp = 0; jp < 2; ++jp)
                ast(st + sb + 128 + sl0 + jp * 16,
                    fmaf(Ab[jp], hin[jp], Bb[jp]));
        }
        __threadfence();
        if (lane == 0)
            __hip_atomic_store(flags + fidx, 2, __ATOMIC_RELEASE,
                               __HIP_MEMORY_SCOPE_AGENT);

        // share h_in with wm0 waves; own start = W0(h_in)
        if (lane < 16) {
#pragma unroll
            for (int jp = 0; jp < 2; ++jp)
                ldsf[128 + sl0 + jp * 16] = hin[jp];
        }
#pragma unroll
        for (int jp = 0; jp < 2; ++jp)
            hws[jp] = fmaf(A0[jp], hin[jp], B0[jp]);
    }
    __syncthreads();
    if (!wm) {
#pragma unroll
        for (int jp = 0; jp < 2; ++jp)
            hws[jp] = ldsf[128 + sl0 + jp * 16];
    }

    // ---- replay: h = a*h + v, write out directly --------------------------
    const int cw = (n0 + wn) >> 1;       // wave's base channel
#pragma unroll
    for (int i = 0; i < 4; ++i) {
        float h0[2];
#pragma unroll
        for (int jp = 0; jp < 2; ++jp)
            h0[jp] = fmaf(Aex[i][jp], hws[jp], Bex[i][jp]);
#pragma unroll
        for (int r = 0; r < 4; ++r) {
            const int row = m0 + wm + i * 16 + quad * 4 + r;
            float* po = out + (size_t)row * H_DIM + cw + lane15;
#pragma unroll
            for (int jp = 0; jp < 2; ++jp) {
                const float2 f = __half22float2(av[i][r][jp]);
                h0[jp] = fmaf(f.x, h0[jp], f.y);
                __builtin_nontemporal_store(h0[jp], po + jp * 16);
            }
        }
    }
}

// ---------------------------------------------------------------------------
extern "C" void kernel_launch(void* const* d_in, const int* in_sizes, int n_in,
                              void* d_out, int out_size, void* d_ws, size_t ws_size,
                              hipStream_t stream)
{
    const float* X    = (const float*)d_in[0];   // x  (8,4096,1024) fp32
    const float* Wm   = (const float*)d_in[1];   // W  (2048,1024)   fp32
    const float* bias = (const float*)d_in[2];   // b  (2048)        fp32
    const float* hx   = (const float*)d_in[3];   // hx (8,1024)      fp32
    float* out = (float*)d_out;                  // (8,4096,1024)    fp32

    char* ws = (char*)d_ws;
    ushort_t* wb    = (ushort_t*)ws;                                //  4 MiB
    ushort_t* xb    = (ushort_t*)(ws + (size_t)O_DIM * K_DIM * 2);  // 64 MiB
    float*    biasp = (float*)(ws + (size_t)(4 + 64) * 1024 * 1024);//  8 KiB
    float*    st    = biasp + 64 * 1024 / 4;                        //  3 MiB
    int*      flags = (int*)(st + (size_t)NTILES * 192);            // 33 KiB

    init_sync<<<(NTILES * 2 + 256) / 256 + 1, 256, 0, stream>>>(flags);
    cvt_w_perm<<<O_DIM * K_DIM / 8 / 256, 256, 0, stream>>>(Wm, wb);
    bias_perm<<<O_DIM / 256, 256, 0, stream>>>(bias, biasp);
    cvt_f32_bf16<<<M_TOT * K_DIM / 8 / 256, 256, 0, stream>>>(X, xb);

    gemm_scan<<<NTILES, 256, 0, stream>>>(xb, wb, biasp, hx, out, st, flags);
}

// Round 5
// 478.121 us; speedup vs baseline: 3.1922x; 3.1922x over previous
//
#include <hip/hip_runtime.h>
#include <hip/hip_bf16.h>
#include <hip/hip_fp16.h>

// ============================================================================
// MinGRUCell forward, MI355X (gfx950).  Round 10 = revert to round-8 (best,
// 443us) + instrumentation: GEMM split into 4 quarter-dispatches (~47us each)
// so any non-GEMM kernel >47us surfaces in the rocprof top-5.  bias_perm
// merged into cvt_w_perm (-1 launch).
//
// Round-9 single-pass lookback failed structurally (1526us, MfmaUtil 4.2% =
// GEMM at normal rate but blocks stretched 8.5x spinning on the 32-deep
// m-chain while holding CU slots).  Reverted.
//
//   zh = x @ W'^T + b'   (W rows permuted: z/h 16-col blocks alternate)
//   GEMM epilogue: a = sigmoid(-z), v = sigmoid(z)*g(h_inter) -> avbuf half2,
//     + per-32-row-chunk affine summaries via in-register quad butterfly
//   phase2: compose 128 chunk summaries per channel, seeded with hx
//   phase3: pure replay h = fma(a,h,v), nontemporal f32 stores
//
// Workspace: wb bf16 4MiB | avbuf half2 128MiB | seed 4MiB | biasp 8KB
// d_out scratch (until phase3 overwrites): xb [0,64Mi) | Aar,Bar [64,72Mi)
// ============================================================================

#define N_B   8
#define L_SEQ 4096
#define H_DIM 1024
#define K_DIM 1024
#define O_DIM 2048
#define M_TOT (N_B * L_SEQ)      // 32768 GEMM rows

#define BM 128
#define BN 128
#define BK 64

#define NCHUNK 128
#define CLEN   (L_SEQ / NCHUNK)  // 32
#define NCH    (N_B * H_DIM)     // 8192 channels

typedef unsigned short ushort_t;
typedef unsigned short us8 __attribute__((ext_vector_type(8)));
typedef __bf16 v8bf __attribute__((ext_vector_type(8)));
typedef float f32x4 __attribute__((ext_vector_type(4)));

static __device__ __forceinline__ ushort_t f2bf(float f) {
    __hip_bfloat16 h = __float2bfloat16(f);   // RTN
    return *reinterpret_cast<ushort_t*>(&h);
}

// async global->LDS DMA, 16B per lane, LDS dest = wave-uniform base + lane*16
static __device__ __forceinline__ void dma16(const ushort_t* g, ushort_t* l) {
    __builtin_amdgcn_global_load_lds(
        (const __attribute__((address_space(1))) unsigned int*)g,
        (__attribute__((address_space(3))) unsigned int*)l,
        16, 0, 0);
}

// ---------------------------------------------------------------------------
// fp32 -> bf16 (8 elems/thread), straight copy (used for X)
// ---------------------------------------------------------------------------
__global__ __launch_bounds__(256) void cvt_f32_bf16(
    const float* __restrict__ src, ushort_t* __restrict__ dst)
{
    const int i = blockIdx.x * 256 + threadIdx.x;
    const float4 f0 = ((const float4*)src)[2 * i];
    const float4 f1 = ((const float4*)src)[2 * i + 1];
    us8 o;
    o[0] = f2bf(f0.x); o[1] = f2bf(f0.y); o[2] = f2bf(f0.z); o[3] = f2bf(f0.w);
    o[4] = f2bf(f1.x); o[5] = f2bf(f1.y); o[6] = f2bf(f1.z); o[7] = f2bf(f1.w);
    ((us8*)dst)[i] = o;
}

// ---------------------------------------------------------------------------
// fp32 -> bf16 W with row permutation + bias permutation (merged).
// dest row o' in 16-row blocks B=o'>>4, t=o'&15:
//   B even -> z row (B>>1)*16+t ; B odd -> h row 1024+(B>>1)*16+t.
// ---------------------------------------------------------------------------
__global__ __launch_bounds__(256) void cvt_w_perm(
    const float* __restrict__ src, ushort_t* __restrict__ dst,
    const float* __restrict__ b, float* __restrict__ bp)
{
    const int i  = blockIdx.x * 256 + threadIdx.x;  // 262144 threads
    const int op = i >> 7;                          // dest row 0..2047
    const int k  = (i & 127) * 8;
    const int B  = op >> 4, t = op & 15;
    const int orig = (B & 1) * 1024 + (B >> 1) * 16 + t;
    const float4* s = (const float4*)(src + (size_t)orig * K_DIM + k);
    const float4 f0 = s[0], f1 = s[1];
    us8 o;
    o[0] = f2bf(f0.x); o[1] = f2bf(f0.y); o[2] = f2bf(f0.z); o[3] = f2bf(f0.w);
    o[4] = f2bf(f1.x); o[5] = f2bf(f1.y); o[6] = f2bf(f1.z); o[7] = f2bf(f1.w);
    *(us8*)(dst + (size_t)op * K_DIM + k) = o;

    if (i < O_DIM) {                                // fused bias permutation
        const int Bb = i >> 4, tb = i & 15;
        bp[i] = b[(Bb & 1) * 1024 + (Bb >> 1) * 16 + tb];
    }
}

// ---------------------------------------------------------------------------
// Gating math.  a = sigmoid(-z), v = sigmoid(z)*g(hi)
// g(x) = x+0.5 (x>=0) else sigmoid(x)
// ---------------------------------------------------------------------------
__device__ __forceinline__ void gate_av(float z, float hi, float& a, float& v)
{
    const float e  = __expf(-z);
    const float sz = 1.0f / (1.0f + e);        // sigmoid(z)
    a = e * sz;                                // sigmoid(-z)
    const float g = (hi >= 0.0f) ? (hi + 0.5f)
                                 : (1.0f / (1.0f + __expf(-hi)));
    v = sz * g;
}

// ---------------------------------------------------------------------------
// GEMM (m97 structure) + fused gate/phase1 epilogue.  Launched 4x with
// mbase = 0/64/128/192 (in BM units) purely so each dispatch ~47us and the
// rocprof top-5 exposes the non-GEMM kernels.
// ---------------------------------------------------------------------------
__global__ __launch_bounds__(256) void gemm_zh(
    const ushort_t* __restrict__ Xb,       // (M_TOT, K) bf16 bits
    const ushort_t* __restrict__ Wb,       // (O_DIM, K) bf16 bits, PERMUTED
    const float* __restrict__ biasp,       // (O_DIM) fp32, PERMUTED
    __half2* __restrict__ avbuf,           // (M_TOT, H_DIM) half2 {a,v}
    float* __restrict__ Aar,               // (NCHUNK, NCH) chunk A
    float* __restrict__ Bar,               // (NCHUNK, NCH) chunk B
    int mbase)                             // m-tile offset (BM units)
{
    __shared__ ushort_t As[BM * BK];
    __shared__ ushort_t Bs[BN * BK];

    const int tid    = threadIdx.x;
    const int wave   = tid >> 6;
    const int lane   = tid & 63;
    const int lane15 = lane & 15;
    const int quad   = lane >> 4;

    const int n0 = blockIdx.x * BN;        // O-tile fast -> A-tile L2 reuse
    const int m0 = (blockIdx.y + mbase) * BM;

    const int lrow = lane >> 3;            // 0..7
    const int jj   = (lane & 7) ^ lrow;    // global chunk (xor swizzle)
    const ushort_t* gA = Xb + (size_t)(m0 + wave * 8 + lrow) * K_DIM + jj * 8;
    const ushort_t* gB = Wb + (size_t)(n0 + wave * 8 + lrow) * K_DIM + jj * 8;
    ushort_t* lA = &As[(wave * 8) * BK];
    ushort_t* lB = &Bs[(wave * 8) * BK];

    const int wm = (wave >> 1) * 64;
    const int wn = (wave & 1) * 64;

    int offA[2][4], offB[2][4];
#pragma unroll
    for (int s = 0; s < 2; ++s) {
#pragma unroll
        for (int t = 0; t < 4; ++t) {
            const int rowA = wm + t * 16 + lane15;
            offA[s][t] = rowA * BK + (((s * 4 + quad) ^ (rowA & 7)) * 8);
            const int rowB = wn + t * 16 + lane15;
            offB[s][t] = rowB * BK + (((s * 4 + quad) ^ (rowB & 7)) * 8);
        }
    }

    const f32x4 fzero = {0.f, 0.f, 0.f, 0.f};
    f32x4 acc[4][4];
#pragma unroll
    for (int i = 0; i < 4; ++i)
#pragma unroll
        for (int j = 0; j < 4; ++j)
            acc[i][j] = fzero;

    for (int kt = 0; kt < K_DIM / BK; ++kt) {
        __syncthreads();
#pragma unroll
        for (int r = 0; r < 4; ++r) {
            dma16(gA + (size_t)r * 32 * K_DIM + kt * BK, lA + r * 32 * BK);
            dma16(gB + (size_t)r * 32 * K_DIM + kt * BK, lB + r * 32 * BK);
        }
        __syncthreads();

#pragma unroll
        for (int s = 0; s < 2; ++s) {
            v8bf af[4], bfr[4];
#pragma unroll
            for (int t = 0; t < 4; ++t) af[t]  = *(const v8bf*)(&As[offA[s][t]]);
#pragma unroll
            for (int t = 0; t < 4; ++t) bfr[t] = *(const v8bf*)(&Bs[offB[s][t]]);
#pragma unroll
            for (int i = 0; i < 4; ++i)
#pragma unroll
                for (int j = 0; j < 4; ++j)
                    acc[i][j] = __builtin_amdgcn_mfma_f32_16x16x32_bf16(
                        af[i], bfr[j], acc[i][j], 0, 0, 0);
        }
    }

    // ---- fused epilogue ---------------------------------------------------
    // columns: j even = z-block, j odd = h-block of same 16 channels.
    float bv[4];
#pragma unroll
    for (int j = 0; j < 4; ++j)
        bv[j] = biasp[n0 + wn + j * 16 + lane15];

    const int chbase = ((n0 + wn) >> 1) + lane15;   // + jp*16

    float Ai[4][2], Bi[4][2];   // per-(i-frag, jp) 16-row affine summaries

#pragma unroll
    for (int i = 0; i < 4; ++i) {
        float A[2] = {1.f, 1.f};
        float Bc[2] = {0.f, 0.f};
#pragma unroll
        for (int r = 0; r < 4; ++r) {
            const size_t row = (size_t)(m0 + wm + i * 16 + quad * 4 + r);
            __half2* prow = avbuf + row * H_DIM + chbase;
#pragma unroll
            for (int jp = 0; jp < 2; ++jp) {
                const float z  = acc[i][2 * jp][r]     + bv[2 * jp];
                const float hh = acc[i][2 * jp + 1][r] + bv[2 * jp + 1];
                float a, v;
                gate_av(z, hh, a, v);
                const __half2 h2 = __floats2half2_rn(a, v);
                prow[jp * 16] = h2;
                // compose with the SAME fp16-rounded values phase3 will use
                const float2 f = __half22float2(h2);
                Bc[jp] = fmaf(f.x, Bc[jp], f.y);
                A[jp] *= f.x;
            }
        }
        // ordered compose across quads (rows i*16 + quad*4 + r are
        // (quad,r)-lexicographic): butterfly on lane bits 16 and 32.
#pragma unroll
        for (int jp = 0; jp < 2; ++jp) {
#pragma unroll
            for (int d = 16; d < 64; d <<= 1) {
                const float Ay = __shfl_xor(A[jp],  d);
                const float By = __shfl_xor(Bc[jp], d);
                // bit set -> I am the LATER block: (A,B) o (Ay,By)
                Bc[jp] = (lane & d) ? fmaf(A[jp], By, Bc[jp])
                                    : fmaf(Ay, Bc[jp], By);
                A[jp] *= Ay;
            }
            Ai[i][jp] = A[jp];
            Bi[i][jp] = Bc[jp];
        }
    }

    // chunk (32 rows) = frags {2cc, 2cc+1}; all quads hold identical values,
    // quad 0 writes.
    if (lane < 16) {
#pragma unroll
        for (int cc = 0; cc < 2; ++cc) {
            const int grow = m0 + wm + cc * 32;
            const int n    = grow >> 12;            // batch
            const int cch  = (grow & (L_SEQ - 1)) >> 5;   // chunk id
            const size_t o = (size_t)cch * NCH + (size_t)n * H_DIM + chbase;
#pragma unroll
            for (int jp = 0; jp < 2; ++jp) {
                const float A0 = Ai[2 * cc][jp],     B0 = Bi[2 * cc][jp];
                const float A1 = Ai[2 * cc + 1][jp], B1 = Bi[2 * cc + 1][jp];
                Aar[o + jp * 16] = A1 * A0;
                Bar[o + jp * 16] = fmaf(A1, B0, B1);
            }
        }
    }
}

// ---------------------------------------------------------------------------
// Phase 2: compose NCHUNK chunk summaries per channel, seeded with hx (fp32).
// ---------------------------------------------------------------------------
__global__ __launch_bounds__(256) void scan_phase2(
    const float* __restrict__ Aar, const float* __restrict__ Bar,
    const float* __restrict__ hx, float* __restrict__ seed)
{
    const int ch = blockIdx.x * 256 + threadIdx.x;    // 0..8191
    float carry = hx[ch];
#pragma unroll 8
    for (int c = 0; c < NCHUNK; ++c) {
        seed[c * NCH + ch] = carry;
        carry = fmaf(Aar[c * NCH + ch], carry, Bar[c * NCH + ch]);
    }
}

// ---------------------------------------------------------------------------
// Phase 3: pure replay from seed: h = fma(a, h, v).  4 ch/thread, 16B av
// loads, nontemporal fp32 stores.
// ---------------------------------------------------------------------------
__global__ __launch_bounds__(256) void scan_phase3(
    const __half2* __restrict__ avbuf,
    const float* __restrict__ seed, float* __restrict__ out)
{
    const int idx = blockIdx.x * 256 + threadIdx.x;
    const int h4  = (idx & 255) << 2;
    const int n   = (idx >> 8) & 7;
    const int c   = idx >> 11;
    const size_t base = ((size_t)(n * L_SEQ + c * CLEN)) * H_DIM + h4;
    const float4* avp = (const float4*)(avbuf + base);  // 4 half2 = 16B
    float* op = out + base;

    const size_t so = (size_t)c * NCH + n * H_DIM + h4;
    float h0[4];
    *(f32x4*)h0 = *(const f32x4*)(seed + so);

#pragma unroll 8
    for (int s = 0; s < CLEN; ++s) {
        float4 avr = avp[(size_t)s * (H_DIM / 4)];
        const __half2* a2 = (const __half2*)&avr;
#pragma unroll
        for (int j = 0; j < 4; ++j) {
            const float2 av = __half22float2(a2[j]);
            h0[j] = fmaf(av.x, h0[j], av.y);
        }
        f32x4 hv = *(const f32x4*)h0;
        __builtin_nontemporal_store(hv, (f32x4*)(op + (size_t)s * H_DIM));
    }
}

// ---------------------------------------------------------------------------
extern "C" void kernel_launch(void* const* d_in, const int* in_sizes, int n_in,
                              void* d_out, int out_size, void* d_ws, size_t ws_size,
                              hipStream_t stream)
{
    const float* X    = (const float*)d_in[0];   // x  (8,4096,1024) fp32
    const float* Wm   = (const float*)d_in[1];   // W  (2048,1024)   fp32
    const float* bias = (const float*)d_in[2];   // b  (2048)        fp32
    const float* hx   = (const float*)d_in[3];   // hx (8,1024)      fp32
    float* out = (float*)d_out;                  // (8,4096,1024)    fp32

    char* ws = (char*)d_ws;
    ushort_t* wb   = (ushort_t*)ws;                                 //   4 MiB
    __half2*  avbuf = (__half2*)(ws + (size_t)O_DIM * K_DIM * 2);   // 128 MiB
    float*    seed = (float*)((char*)avbuf + (size_t)M_TOT * H_DIM * 4); // 4 MiB
    float*    biasp = seed + (size_t)NCHUNK * NCH;                  //   8 KiB

    // d_out (128 MiB) doubles as scratch until phase3 overwrites it:
    //   bytes [0, 64Mi):   x_bf16  (M_TOT*K_DIM*2 B = exactly half)
    //   bytes [64Mi,72Mi): Aar, Bar (NCHUNK*NCH fp32 each)
    ushort_t* xb = (ushort_t*)d_out;
    float* Aar = out + (size_t)M_TOT * H_DIM / 2;      // true halfway point
    float* Bar = Aar + (size_t)NCHUNK * NCH;

    cvt_w_perm<<<O_DIM * K_DIM / 8 / 256, 256, 0, stream>>>(Wm, wb, bias, biasp);
    cvt_f32_bf16<<<M_TOT * K_DIM / 8 / 256, 256, 0, stream>>>(X, xb);

    dim3 ggrid(O_DIM / BN, (M_TOT / BM) / 4);    // (16, 64) per quarter
    for (int q = 0; q < 4; ++q)
        gemm_zh<<<ggrid, 256, 0, stream>>>(xb, wb, biasp, avbuf, Aar, Bar,
                                           q * 64);

    scan_phase2<<<NCH / 256, 256, 0, stream>>>(Aar, Bar, hx, seed);

    const int p3_blocks = (NCH / 4) * NCHUNK / 256;    // 1024
    scan_phase3<<<p3_blocks, 256, 0, stream>>>(avbuf, seed, out);
}